// Round 1
// 143.634 us; speedup vs baseline: 1.0699x; 1.0699x over previous
//
#include <hip/hip_runtime.h>
#include <hip/hip_bf16.h>

// KANLayer: out = x @ Wb^T + silu(x) @ sum_g(Ws)^T
// One packed bf16 GEMM, K=2048: A'=[x|silu(x)], W'=[Wb|sum_g Ws], out=A'@W'^T.
// R9: deep-pipelined GEMM (T3+T4 counted-vmcnt), replacing R8's depth-1
//     reg-staged loop (which drained vmcnt(0)+lgkmcnt(0) every K-window ->
//     latency-bound: MfmaUtil 24%, VALUBusy 9.5%, HBM 15%, all pipes idle).
//  - BM=256 x BN=128, BK=64, 8 waves of 64x64 -> grid 256 = 1 block/CU.
//  - global_load_lds dwordx4 staging (no ds_write traffic, no reg round-trip).
//  - 3-deep LDS ring (144 KB): stage tile s+2 at top of step s; s_waitcnt
//    vmcnt(6) (never 0 in steady state) + raw s_barrier -> ~2 K-steps of
//    MFMA cover each tile's load latency.
//  - both-sides XOR swizzle (rule 21): LDS [row][chunk^(row&7)] filled by
//    pre-swizzling the per-lane GLOBAL k-chunk (stays inside the row's 128B
//    segment -> coalescing kept); ds_read_b128 applies same XOR ->
//    conflict-free (8 lanes per bank-group = wave64 b128 minimum).
//  - s_setprio(1) around MFMA clusters (T5), XCD-swizzled block mapping (T1).

#define BATCH 8192
#define IN_F 1024
#define OUT_F 1024
#define KP 2048

typedef unsigned short ushort_t;
typedef __attribute__((ext_vector_type(8))) short short8;
typedef __attribute__((ext_vector_type(4))) float f32x4;

__device__ __forceinline__ ushort_t f2bf(float f) {
  union { float f; unsigned int u; } v;
  v.f = f;
  unsigned int u = v.u;
  u += 0x7fffu + ((u >> 16) & 1u);  // RNE
  return (ushort_t)(u >> 16);
}

// ---------------- merged prep (unchanged: ~traffic floor) -----------
#define PREP_A_BLOCKS 4096
#define PREP_S_BLOCKS 1024
#define PREP_B_BLOCKS 1024
#define PREP_BLOCKS (PREP_A_BLOCKS + PREP_S_BLOCKS + PREP_B_BLOCKS)

__global__ __launch_bounds__(256) void prep_all(
    const float* __restrict__ x, const float* __restrict__ Wb,
    const float* __restrict__ Ws, ushort_t* __restrict__ Apack,
    ushort_t* __restrict__ Wpack) {
  const int blk = blockIdx.x;
  const int t = threadIdx.x;

  if (blk < PREP_A_BLOCKS) {
    const int idx = blk * 256 + t;
    const int b = idx >> 7;
    const int i = (idx & 127) << 3;
    const float4 x0 = *(const float4*)(x + ((size_t)b << 10) + i);
    const float4 x1 = *(const float4*)(x + ((size_t)b << 10) + i + 4);
    float xv[8] = {x0.x, x0.y, x0.z, x0.w, x1.x, x1.y, x1.z, x1.w};
    ushort_t vb[8], vs[8];
#pragma unroll
    for (int j = 0; j < 8; ++j) {
      vb[j] = f2bf(xv[j]);
      vs[j] = f2bf(xv[j] / (1.0f + __expf(-xv[j])));
    }
    ushort_t* row = Apack + ((size_t)b << 11);
    *(short8*)(row + i) = *(short8*)vb;
    *(short8*)(row + IN_F + i) = *(short8*)vs;
  } else if (blk < PREP_A_BLOCKS + PREP_S_BLOCKS) {
    const int idx = (blk - PREP_A_BLOCKS) * 256 + t;
    const int o = idx >> 8;
    const int i0 = (idx & 255) << 2;
    ushort_t vs[4];
#pragma unroll
    for (int j = 0; j < 4; ++j) {
      const float4* p = (const float4*)(Ws + ((((size_t)o << 10) + i0 + j) << 3));
      const float4 a = p[0];
      const float4 b = p[1];
      vs[j] = f2bf(((a.x + a.y) + (a.z + a.w)) + ((b.x + b.y) + (b.z + b.w)));
    }
    *(ushort4*)(Wpack + ((size_t)o << 11) + IN_F + i0) = *(ushort4*)vs;
  } else {
    const int idx = (blk - PREP_A_BLOCKS - PREP_S_BLOCKS) * 256 + t;
    const int o = idx >> 8;
    const int c = (idx & 255) << 2;
    const float4 w = *(const float4*)(Wb + ((size_t)o << 10) + c);
    ushort4 v;
    v.x = f2bf(w.x); v.y = f2bf(w.y); v.z = f2bf(w.z); v.w = f2bf(w.w);
    *(ushort4*)(Wpack + ((size_t)o << 11) + c) = v;
  }
}

// ---------------- GEMM ----------------
#define BM 256
#define BN 128
#define GBK 64
#define NSTEP (KP / GBK)       // 32
#define A_US 16384             // A region: 256 rows x 64 (ushorts) = 32 KB
#define B_US 8192              // B region: 128 rows x 64 = 16 KB
#define BUF_US (A_US + B_US)   // 24576 ushorts = 48 KB per ring slot
#define NBUF 3                 // 144 KB LDS ring

typedef const __attribute__((address_space(1))) unsigned int gas_uint;
typedef __attribute__((address_space(3))) unsigned int las_uint;
#define ASYNC16(l, g) \
  __builtin_amdgcn_global_load_lds((gas_uint*)(g), (las_uint*)(l), 16, 0, 0)

__device__ __forceinline__ void stage_tile(const ushort_t* ga, const ushort_t* gb,
                                           ushort_t* la, ushort_t* lb,
                                           size_t rskip) {
  // 6 x global_load_lds_dwordx4 per thread: A rows (4 x 64-row slabs), B (2).
  ASYNC16(la, ga);
  ASYNC16(la + 4096, ga + rskip);
  ASYNC16(la + 8192, ga + 2 * rskip);
  ASYNC16(la + 12288, ga + 3 * rskip);
  ASYNC16(lb, gb);
  ASYNC16(lb + 4096, gb + rskip);
}

__device__ __forceinline__ void mfma_step(const ushort_t* __restrict__ ab,
                                          const ushort_t* __restrict__ bb,
                                          const int (&aoff)[2][4],
                                          const int (&boff)[2][4],
                                          f32x4 (&acc)[4][4]) {
#pragma unroll
  for (int kk = 0; kk < 2; ++kk) {
    short8 af[4], bf[4];
#pragma unroll
    for (int i = 0; i < 4; ++i) af[i] = *(const short8*)(ab + aoff[kk][i]);
#pragma unroll
    for (int i = 0; i < 4; ++i) bf[i] = *(const short8*)(bb + boff[kk][i]);
    __builtin_amdgcn_s_setprio(1);
#pragma unroll
    for (int mi = 0; mi < 4; ++mi)
#pragma unroll
      for (int ni = 0; ni < 4; ++ni)
        acc[mi][ni] = __builtin_amdgcn_mfma_f32_16x16x32_bf16(
            af[mi], bf[ni], acc[mi][ni], 0, 0, 0);
    __builtin_amdgcn_s_setprio(0);
  }
}

__global__ __launch_bounds__(512, 2) void gemm_packed(
    const ushort_t* __restrict__ A,  // [BATCH][KP]
    const ushort_t* __restrict__ W,  // [OUT_F][KP]
    float* __restrict__ C) {         // [BATCH][OUT_F]
  __shared__ __align__(16) ushort_t lds[NBUF * BUF_US];  // 144 KB

  const int t = threadIdx.x;
  const int flat = blockIdx.x;           // 0..255
  const int xcd = flat & 7;
  const int local = flat >> 3;           // 0..31
  const int nt = local >> 2;             // 0..7
  const int mt = xcd * 4 + (local & 3);  // 0..31 (XCD-local A slabs)

  const int lane = t & 63;
  const int wave = t >> 6;  // 0..7
  const int wr = wave >> 1; // 0..3 (M)
  const int wc = wave & 1;  // 0..1 (N)
  const int lr = lane & 15;
  const int lq = lane >> 4;

  // ---- staging addresses (source-side swizzle) ----
  // thread t -> LDS linear slot (row = t>>3, phys chunk = t&7); the global
  // k-chunk it must fetch is phys ^ (row&7). Threads 8r..8r+7 stay inside
  // row r's 128B segment -> coalesced.
  const int srow = t >> 3;               // 0..63
  const int kc = (t & 7) ^ (srow & 7);   // swizzled source k-chunk
  const ushort_t* ga = A + (size_t)(mt * BM + srow) * KP + kc * 8;
  const ushort_t* gb = W + (size_t)(nt * BN + srow) * KP + kc * 8;
  const int ldst = t * 8;                // ushort offset (t*16 B)
  const size_t rskip = (size_t)64 * KP;

  // ---- fragment read offsets (read-side swizzle, ushorts) ----
  // mfma_f32_16x16x32_bf16 A/B frag: lane holds row (lane&15), k-chunk
  // (lane>>4)*8 within each K=32 half; chunk index in row = kk*4 + lq.
  int aoff[2][4], boff[2][4];
#pragma unroll
  for (int kk = 0; kk < 2; ++kk)
#pragma unroll
    for (int i = 0; i < 4; ++i) {
      const int arow = wr * 64 + i * 16 + lr;
      const int brow = wc * 64 + i * 16 + lr;
      const int ks = kk * 4 + lq;
      aoff[kk][i] = arow * 64 + ((ks ^ (arow & 7)) << 3);
      boff[kk][i] = brow * 64 + ((ks ^ (brow & 7)) << 3);
    }

  f32x4 acc[4][4];
#pragma unroll
  for (int mi = 0; mi < 4; ++mi)
#pragma unroll
    for (int ni = 0; ni < 4; ++ni) acc[mi][ni] = (f32x4){0.f, 0.f, 0.f, 0.f};

  // ---- prologue: tiles 0,1 in flight; wait tile 0 only ----
  stage_tile(ga, gb, lds + ldst, lds + A_US + ldst, rskip);
  stage_tile(ga + GBK, gb + GBK, lds + BUF_US + ldst, lds + BUF_US + A_US + ldst,
             rskip);
  asm volatile("s_waitcnt vmcnt(6)" ::: "memory");
  __builtin_amdgcn_s_barrier();
  __builtin_amdgcn_sched_barrier(0);

  // ---- main loop: stage s+2 | compute s | vmcnt(6) barrier ----
  int co = 0;                 // current ring offset
  int so = 2 * BUF_US;        // stage ring offset (tile s+2)
  const ushort_t* gpa = ga + 2 * GBK;
  const ushort_t* gpb = gb + 2 * GBK;
#pragma unroll 3
  for (int s = 0; s < NSTEP - 2; ++s) {
    stage_tile(gpa, gpb, lds + so + ldst, lds + so + A_US + ldst, rskip);
    gpa += GBK;
    gpb += GBK;
    mfma_step(lds + co, lds + co + A_US, aoff, boff, acc);
    // tile s+1 must be resident; tile s+2's 6 loads stay in flight.
    asm volatile("s_waitcnt vmcnt(6)" ::: "memory");
    __builtin_amdgcn_s_barrier();
    __builtin_amdgcn_sched_barrier(0);
    co += BUF_US; if (co == NBUF * BUF_US) co = 0;
    so += BUF_US; if (so == NBUF * BUF_US) so = 0;
  }
  // ---- tail: step NSTEP-2 (drain last tile), step NSTEP-1 ----
  mfma_step(lds + co, lds + co + A_US, aoff, boff, acc);
  asm volatile("s_waitcnt vmcnt(0)" ::: "memory");
  __builtin_amdgcn_s_barrier();
  __builtin_amdgcn_sched_barrier(0);
  co += BUF_US; if (co == NBUF * BUF_US) co = 0;
  mfma_step(lds + co, lds + co + A_US, aoff, boff, acc);

  // ---- epilogue: C/D layout col=lane&15, row=(lane>>4)*4+reg ----
  const int col0 = nt * BN + wc * 64 + lr;
  const int row0 = mt * BM + wr * 64 + (lq << 2);
#pragma unroll
  for (int mi = 0; mi < 4; ++mi)
#pragma unroll
    for (int ni = 0; ni < 4; ++ni) {
      float* cp = C + (size_t)(row0 + mi * 16) * OUT_F + col0 + ni * 16;
#pragma unroll
      for (int rr = 0; rr < 4; ++rr) cp[(size_t)rr * OUT_F] = acc[mi][ni][rr];
    }
}

extern "C" void kernel_launch(void* const* d_in, const int* in_sizes, int n_in,
                              void* d_out, int out_size, void* d_ws, size_t ws_size,
                              hipStream_t stream) {
  const float* x = (const float*)d_in[0];
  const float* wb = (const float*)d_in[1];
  const float* ws = (const float*)d_in[2];
  float* out = (float*)d_out;

  ushort_t* Apack = (ushort_t*)d_ws;                                    // 33.5 MB
  ushort_t* Wpack = (ushort_t*)((char*)d_ws + (size_t)BATCH * KP * 2);  // +4 MB

  prep_all<<<PREP_BLOCKS, 256, 0, stream>>>(x, wb, ws, Apack, Wpack);
  gemm_packed<<<dim3((BATCH / BM) * (OUT_F / BN)), dim3(512), 0, stream>>>(Apack, Wpack, out);
}

// Round 2
// 140.764 us; speedup vs baseline: 1.0917x; 1.0204x over previous
//
#include <hip/hip_runtime.h>
#include <hip/hip_bf16.h>

// KANLayer: out = x @ Wb^T + silu(x) @ sum_g(Ws)^T
// One packed bf16 GEMM, K=2048: A'=[x|silu(x)], W'=[Wb|sum_g Ws], out=A'@W'^T.
// R10: T3 phase-split. R9's single barrier/K-step convoy-aligned all 8 waves
//      (all ds_read, then all MFMA -> pipes alternate ~sum instead of ~max).
//      Now each K-step = 4 phases: {ds_read quadrant | stage 2 gload_lds} ->
//      s_barrier -> lgkmcnt(0) -> 8 MFMA (setprio-wrapped) -> s_barrier.
//      Reads issued pre-barrier drain under other waves' MFMA clusters.
//      Counted vmcnt(6) once/step (T4), both-sides XOR swizzle (T2),
//      XCD-swizzled blocks (T1), setprio (T5) retained from R9.

#define BATCH 8192
#define IN_F 1024
#define OUT_F 1024
#define KP 2048

typedef unsigned short ushort_t;
typedef __attribute__((ext_vector_type(8))) short short8;
typedef __attribute__((ext_vector_type(4))) float f32x4;

__device__ __forceinline__ ushort_t f2bf(float f) {
  union { float f; unsigned int u; } v;
  v.f = f;
  unsigned int u = v.u;
  u += 0x7fffu + ((u >> 16) & 1u);  // RNE
  return (ushort_t)(u >> 16);
}

// ---------------- merged prep (unchanged: ~traffic floor) -----------
#define PREP_A_BLOCKS 4096
#define PREP_S_BLOCKS 1024
#define PREP_B_BLOCKS 1024
#define PREP_BLOCKS (PREP_A_BLOCKS + PREP_S_BLOCKS + PREP_B_BLOCKS)

__global__ __launch_bounds__(256) void prep_all(
    const float* __restrict__ x, const float* __restrict__ Wb,
    const float* __restrict__ Ws, ushort_t* __restrict__ Apack,
    ushort_t* __restrict__ Wpack) {
  const int blk = blockIdx.x;
  const int t = threadIdx.x;

  if (blk < PREP_A_BLOCKS) {
    const int idx = blk * 256 + t;
    const int b = idx >> 7;
    const int i = (idx & 127) << 3;
    const float4 x0 = *(const float4*)(x + ((size_t)b << 10) + i);
    const float4 x1 = *(const float4*)(x + ((size_t)b << 10) + i + 4);
    float xv[8] = {x0.x, x0.y, x0.z, x0.w, x1.x, x1.y, x1.z, x1.w};
    ushort_t vb[8], vs[8];
#pragma unroll
    for (int j = 0; j < 8; ++j) {
      vb[j] = f2bf(xv[j]);
      vs[j] = f2bf(xv[j] / (1.0f + __expf(-xv[j])));
    }
    ushort_t* row = Apack + ((size_t)b << 11);
    *(short8*)(row + i) = *(short8*)vb;
    *(short8*)(row + IN_F + i) = *(short8*)vs;
  } else if (blk < PREP_A_BLOCKS + PREP_S_BLOCKS) {
    const int idx = (blk - PREP_A_BLOCKS) * 256 + t;
    const int o = idx >> 8;
    const int i0 = (idx & 255) << 2;
    ushort_t vs[4];
#pragma unroll
    for (int j = 0; j < 4; ++j) {
      const float4* p = (const float4*)(Ws + ((((size_t)o << 10) + i0 + j) << 3));
      const float4 a = p[0];
      const float4 b = p[1];
      vs[j] = f2bf(((a.x + a.y) + (a.z + a.w)) + ((b.x + b.y) + (b.z + b.w)));
    }
    *(ushort4*)(Wpack + ((size_t)o << 11) + IN_F + i0) = *(ushort4*)vs;
  } else {
    const int idx = (blk - PREP_A_BLOCKS - PREP_S_BLOCKS) * 256 + t;
    const int o = idx >> 8;
    const int c = (idx & 255) << 2;
    const float4 w = *(const float4*)(Wb + ((size_t)o << 10) + c);
    ushort4 v;
    v.x = f2bf(w.x); v.y = f2bf(w.y); v.z = f2bf(w.z); v.w = f2bf(w.w);
    *(ushort4*)(Wpack + ((size_t)o << 11) + c) = v;
  }
}

// ---------------- GEMM ----------------
#define BM 256
#define BN 128
#define GBK 64
#define NSTEP (KP / GBK)       // 32
#define A_US 16384             // A region: 256 rows x 64 ushorts = 32 KB
#define B_US 8192              // B region: 128 rows x 64 = 16 KB
#define BUF_US (A_US + B_US)   // 24576 ushorts = 48 KB per ring slot
#define NBUF 3                 // 144 KB LDS ring

typedef const __attribute__((address_space(1))) unsigned int gas_uint;
typedef __attribute__((address_space(3))) unsigned int las_uint;
#define ASYNC16(l, g) \
  __builtin_amdgcn_global_load_lds((gas_uint*)(g), (las_uint*)(l), 16, 0, 0)

#define LGKM0() do { \
  asm volatile("s_waitcnt lgkmcnt(0)" ::: "memory"); \
  __builtin_amdgcn_sched_barrier(0); \
} while (0)

__global__ __launch_bounds__(512, 2) void gemm_packed(
    const ushort_t* __restrict__ A,  // [BATCH][KP]
    const ushort_t* __restrict__ W,  // [OUT_F][KP]
    float* __restrict__ C) {         // [BATCH][OUT_F]
  __shared__ __align__(16) ushort_t lds[NBUF * BUF_US];  // 144 KB

  const int t = threadIdx.x;
  const int flat = blockIdx.x;           // 0..255
  const int xcd = flat & 7;
  const int local = flat >> 3;           // 0..31
  const int nt = local >> 2;             // 0..7
  const int mt = xcd * 4 + (local & 3);  // 0..31 (XCD-local A slabs)

  const int lane = t & 63;
  const int wave = t >> 6;  // 0..7
  const int wr = wave >> 1; // 0..3 (M)
  const int wc = wave & 1;  // 0..1 (N)
  const int lr = lane & 15;
  const int lq = lane >> 4;

  // ---- staging addresses (source-side swizzle) ----
  // thread t -> LDS linear slot (row = t>>3, phys chunk = t&7); the global
  // k-chunk fetched is phys ^ (row&7): stays inside the row's 128B segment
  // -> coalesced, and read-side applies the same XOR (rule 21).
  const int srow = t >> 3;               // 0..63
  const int kc = (t & 7) ^ (srow & 7);   // swizzled source k-chunk
  const ushort_t* ga = A + (size_t)(mt * BM + srow) * KP + kc * 8;
  const ushort_t* gb = W + (size_t)(nt * BN + srow) * KP + kc * 8;
  const int ldst = t * 8;                // ushort offset (t*16 B)
  const size_t rskip = (size_t)64 * KP;

  // ---- fragment read offsets (read-side swizzle, ushorts) ----
  int aoff[2][4], boff[2][4];
#pragma unroll
  for (int kk = 0; kk < 2; ++kk)
#pragma unroll
    for (int i = 0; i < 4; ++i) {
      const int arow = wr * 64 + i * 16 + lr;
      const int brow = wc * 64 + i * 16 + lr;
      const int ks = kk * 4 + lq;
      aoff[kk][i] = arow * 64 + ((ks ^ (arow & 7)) << 3);
      boff[kk][i] = brow * 64 + ((ks ^ (brow & 7)) << 3);
    }

  f32x4 acc[4][4];
#pragma unroll
  for (int mi = 0; mi < 4; ++mi)
#pragma unroll
    for (int ni = 0; ni < 4; ++ni) acc[mi][ni] = (f32x4){0.f, 0.f, 0.f, 0.f};

  // ---- prologue: tiles 0,1 fully in flight; wait tile 0 only ----
  {
    ushort_t* la = lds + ldst;
    ushort_t* lb = lds + A_US + ldst;
    ASYNC16(la, ga);              ASYNC16(la + 4096, ga + rskip);
    ASYNC16(la + 8192, ga + 2 * rskip); ASYNC16(la + 12288, ga + 3 * rskip);
    ASYNC16(lb, gb);              ASYNC16(lb + 4096, gb + rskip);
    la += BUF_US; lb += BUF_US;
    ASYNC16(la, ga + GBK);              ASYNC16(la + 4096, ga + GBK + rskip);
    ASYNC16(la + 8192, ga + GBK + 2 * rskip); ASYNC16(la + 12288, ga + GBK + 3 * rskip);
    ASYNC16(lb, gb + GBK);              ASYNC16(lb + 4096, gb + GBK + rskip);
  }
  asm volatile("s_waitcnt vmcnt(6)" ::: "memory");
  __builtin_amdgcn_s_barrier();
  __builtin_amdgcn_sched_barrier(0);

  // ---- main loop: 4 phases/step; stage s+2 spread over P0..P2 ----
  int co = 0;                 // compute ring offset (tile s)
  int so = 2 * BUF_US;        // stage ring offset (tile s+2)
  const ushort_t* gpa = ga + 2 * GBK;
  const ushort_t* gpb = gb + 2 * GBK;

#define MFMA8(KK, N0)                                                        \
  do {                                                                       \
    __builtin_amdgcn_s_setprio(1);                                           \
    _Pragma("unroll") for (int mi = 0; mi < 4; ++mi) {                       \
      acc[mi][N0] = __builtin_amdgcn_mfma_f32_16x16x32_bf16(                 \
          af##KK[mi], bf##KK[N0], acc[mi][N0], 0, 0, 0);                     \
      acc[mi][N0 + 1] = __builtin_amdgcn_mfma_f32_16x16x32_bf16(             \
          af##KK[mi], bf##KK[N0 + 1], acc[mi][N0 + 1], 0, 0, 0);             \
    }                                                                        \
    __builtin_amdgcn_s_setprio(0);                                           \
  } while (0)

#pragma unroll 3
  for (int s = 0; s < NSTEP - 2; ++s) {
    const ushort_t* ab = lds + co;
    const ushort_t* bb = lds + co + A_US;
    ushort_t* sa = lds + so + ldst;
    ushort_t* sb = lds + so + A_US + ldst;
    short8 af0[4], af1[4], bf0[4], bf1[4];

    // -- P0: reads {af0[0..3], bf0[0..1]} | stage A slabs 0,1 --
#pragma unroll
    for (int i = 0; i < 4; ++i) af0[i] = *(const short8*)(ab + aoff[0][i]);
    bf0[0] = *(const short8*)(bb + boff[0][0]);
    bf0[1] = *(const short8*)(bb + boff[0][1]);
    ASYNC16(sa, gpa);
    ASYNC16(sa + 4096, gpa + rskip);
    __builtin_amdgcn_s_barrier();
    LGKM0();
    MFMA8(0, 0);
    __builtin_amdgcn_s_barrier();

    // -- P1: reads {bf0[2..3], af1[0..1]} | stage A slabs 2,3 --
    bf0[2] = *(const short8*)(bb + boff[0][2]);
    bf0[3] = *(const short8*)(bb + boff[0][3]);
    af1[0] = *(const short8*)(ab + aoff[1][0]);
    af1[1] = *(const short8*)(ab + aoff[1][1]);
    ASYNC16(sa + 8192, gpa + 2 * rskip);
    ASYNC16(sa + 12288, gpa + 3 * rskip);
    __builtin_amdgcn_s_barrier();
    LGKM0();
    MFMA8(0, 2);
    __builtin_amdgcn_s_barrier();

    // -- P2: reads {af1[2..3], bf1[0..1]} | stage B slabs 0,1 --
    af1[2] = *(const short8*)(ab + aoff[1][2]);
    af1[3] = *(const short8*)(ab + aoff[1][3]);
    bf1[0] = *(const short8*)(bb + boff[1][0]);
    bf1[1] = *(const short8*)(bb + boff[1][1]);
    ASYNC16(sb, gpb);
    ASYNC16(sb + 4096, gpb + rskip);
    __builtin_amdgcn_s_barrier();
    LGKM0();
    MFMA8(1, 0);
    __builtin_amdgcn_s_barrier();

    // -- P3: reads {bf1[2..3]} | vmcnt(6): s+1 resident, s+2 in flight --
    bf1[2] = *(const short8*)(bb + boff[1][2]);
    bf1[3] = *(const short8*)(bb + boff[1][3]);
    __builtin_amdgcn_s_barrier();
    LGKM0();
    MFMA8(1, 2);
    asm volatile("s_waitcnt vmcnt(6)" ::: "memory");
    __builtin_amdgcn_s_barrier();
    __builtin_amdgcn_sched_barrier(0);

    gpa += GBK;
    gpb += GBK;
    co += BUF_US; if (co == NBUF * BUF_US) co = 0;
    so += BUF_US; if (so == NBUF * BUF_US) so = 0;
  }

  // ---- tail: two steps without staging ----
#pragma unroll 1
  for (int s = 0; s < 2; ++s) {
    const ushort_t* ab = lds + co;
    const ushort_t* bb = lds + co + A_US;
    short8 af0[4], af1[4], bf0[4], bf1[4];
#pragma unroll
    for (int kk = 0; kk < 2; ++kk) { (void)kk; }
#pragma unroll
    for (int i = 0; i < 4; ++i) af0[i] = *(const short8*)(ab + aoff[0][i]);
#pragma unroll
    for (int i = 0; i < 4; ++i) bf0[i] = *(const short8*)(bb + boff[0][i]);
#pragma unroll
    for (int i = 0; i < 4; ++i) af1[i] = *(const short8*)(ab + aoff[1][i]);
#pragma unroll
    for (int i = 0; i < 4; ++i) bf1[i] = *(const short8*)(bb + boff[1][i]);
    LGKM0();
    MFMA8(0, 0);
    MFMA8(0, 2);
    MFMA8(1, 0);
    MFMA8(1, 2);
    if (s == 0) {
      asm volatile("s_waitcnt vmcnt(0)" ::: "memory");
      __builtin_amdgcn_s_barrier();
      __builtin_amdgcn_sched_barrier(0);
      co += BUF_US; if (co == NBUF * BUF_US) co = 0;
    }
  }

  // ---- epilogue: C/D layout col=lane&15, row=(lane>>4)*4+reg ----
  const int col0 = nt * BN + wc * 64 + lr;
  const int row0 = mt * BM + wr * 64 + (lq << 2);
#pragma unroll
  for (int mi = 0; mi < 4; ++mi)
#pragma unroll
    for (int ni = 0; ni < 4; ++ni) {
      float* cp = C + (size_t)(row0 + mi * 16) * OUT_F + col0 + ni * 16;
#pragma unroll
      for (int rr = 0; rr < 4; ++rr) cp[(size_t)rr * OUT_F] = acc[mi][ni][rr];
    }
}

extern "C" void kernel_launch(void* const* d_in, const int* in_sizes, int n_in,
                              void* d_out, int out_size, void* d_ws, size_t ws_size,
                              hipStream_t stream) {
  const float* x = (const float*)d_in[0];
  const float* wb = (const float*)d_in[1];
  const float* ws = (const float*)d_in[2];
  float* out = (float*)d_out;

  ushort_t* Apack = (ushort_t*)d_ws;                                    // 33.5 MB
  ushort_t* Wpack = (ushort_t*)((char*)d_ws + (size_t)BATCH * KP * 2);  // +4 MB

  prep_all<<<PREP_BLOCKS, 256, 0, stream>>>(x, wb, ws, Apack, Wpack);
  gemm_packed<<<dim3((BATCH / BM) * (OUT_F / BN)), dim3(512), 0, stream>>>(Apack, Wpack, out);
}